// Round 5
// baseline (461.493 us; speedup 1.0000x reference)
//
#include <hip/hip_runtime.h>
#include <stdint.h>

typedef unsigned short u16t;
typedef unsigned int   u32t;
typedef __attribute__((ext_vector_type(8))) short frag8;   // 8 bf16 = 4 VGPRs
typedef __attribute__((ext_vector_type(4))) float fragc;   // 4 fp32 acc

#define NN 50000
#define NE 800000
#define NB_EDGE 6250           // edge blocks (128 edges each, two 64-edge tiles)
#define NB_NODE 782            // node-MLP blocks (64 nodes each)

// packed-weight offsets in u16 elements within d_ws (weights: 139264 B)
#define W1P 0
#define W2P 24576
#define W3P 40960
#define U1P 49152
#define U2P 61440
// bf16 mirrors of nf/st in d_ws (byte offsets; both 16B-aligned)
#define NFB_OFF 139264                     // u16 nfb[NN*64]  (6.4 MB)
#define STB_OFF (NFB_OFF + 6400000)        // u16 stb[NN*32]  (3.2 MB)

// prep grid partition
#define PB_PACK 34
#define PB_ZERO 3125           // zero out1: NN*16 float4
#define PB_NF   1563           // cvt nf: NN*64 = 3.2M elems, 2048/block
#define PB_ST   782            // cvt st: NN*32 = 1.6M elems

__device__ __forceinline__ u16t f2bf(float f) {
    u32t x = __builtin_bit_cast(u32t, f);
    x = x + 0x7FFFu + ((x >> 16) & 1u);   // RNE
    return (u16t)(x >> 16);
}

__device__ __forceinline__ u32t pack_bf2(float x, float y) {
#if __has_builtin(__builtin_amdgcn_cvt_pk_bf16_f32)
    typedef __attribute__((ext_vector_type(2))) __bf16 bfv2;
    bfv2 r = __builtin_amdgcn_cvt_pk_bf16_f32(x, y);
    return __builtin_bit_cast(u32t, r);
#else
    return (u32t)f2bf(x) | ((u32t)f2bf(y) << 16);
#endif
}

// ---------------------------------------------------------------------------
// Weight prepack core: W (K x N row-major fp32) -> bf16 frag order.
// Packed layout serves as both B-frag (col=lane&15) and A-frag (row=lane&15).
// ---------------------------------------------------------------------------
__device__ __forceinline__ void prepack_one(int t, const float* w1, const float* w2,
                                            const float* w3, const float* u1,
                                            const float* u2, u16t* out) {
    const float* src; u16t* dst; int id, K, N;
    if (t < 3072)      { id = t;        K = 192; N = 128; src = w1; dst = out + W1P; }
    else if (t < 5120) { id = t - 3072; K = 128; N = 128; src = w2; dst = out + W2P; }
    else if (t < 6144) { id = t - 5120; K = 128; N = 64;  src = w3; dst = out + W3P; }
    else if (t < 7680) { id = t - 6144; K = 96;  N = 128; src = u1; dst = out + U1P; }
    else if (t < 8704) { id = t - 7680; K = 128; N = 64;  src = u2; dst = out + U2P; }
    else return;
    int lane = id & 63;
    int fl   = id >> 6;
    int ksteps = K >> 5;
    int nb = fl / ksteps, ks = fl - nb * ksteps;
    int n  = nb * 16 + (lane & 15);
    int k0 = ks * 32 + (lane >> 4) * 8;
    const float* s = src + (size_t)k0 * N + n;
    uint4 v;
    v.x = pack_bf2(s[0],           s[(size_t)N]);
    v.y = pack_bf2(s[2*(size_t)N], s[3*(size_t)N]);
    v.z = pack_bf2(s[4*(size_t)N], s[5*(size_t)N]);
    v.w = pack_bf2(s[6*(size_t)N], s[7*(size_t)N]);
    *(uint4*)(dst + (size_t)id * 8) = v;
}

// fused prep: prepack weights | zero out1 | cvt nf->bf16 | cvt st->bf16
__global__ void prep_k(const float* __restrict__ w1, const float* __restrict__ w2,
                       const float* __restrict__ w3, const float* __restrict__ u1,
                       const float* __restrict__ u2, u16t* __restrict__ wp,
                       float4* __restrict__ out1v,
                       const float* __restrict__ nf, u16t* __restrict__ nfb,
                       const float* __restrict__ st, u16t* __restrict__ stb) {
    int b = blockIdx.x;
    if (b < PB_PACK) {
        prepack_one(b * 256 + threadIdx.x, w1, w2, w3, u1, u2, wp);
    } else if (b < PB_PACK + PB_ZERO) {
        int i = (b - PB_PACK) * 256 + threadIdx.x;
        if (i < NN * 16) out1v[i] = make_float4(0.f, 0.f, 0.f, 0.f);
    } else if (b < PB_PACK + PB_ZERO + PB_NF) {
        int i = ((b - PB_PACK - PB_ZERO) * 256 + threadIdx.x) * 8;
        if (i < NN * 64) {
            float4 a = *(const float4*)(nf + i);
            float4 c = *(const float4*)(nf + i + 4);
            uint4 v;
            v.x = pack_bf2(a.x, a.y); v.y = pack_bf2(a.z, a.w);
            v.z = pack_bf2(c.x, c.y); v.w = pack_bf2(c.z, c.w);
            *(uint4*)(nfb + i) = v;
        }
    } else {
        int i = ((b - PB_PACK - PB_ZERO - PB_NF) * 256 + threadIdx.x) * 8;
        if (i < NN * 32) {
            float4 a = *(const float4*)(st + i);
            float4 c = *(const float4*)(st + i + 4);
            uint4 v;
            v.x = pack_bf2(a.x, a.y); v.y = pack_bf2(a.z, a.w);
            v.z = pack_bf2(c.x, c.y); v.w = pack_bf2(c.z, c.w);
            *(uint4*)(stb + i) = v;
        }
    }
}

// ---------------------------------------------------------------------------
// Fused main kernel — R4 structure + tile-pair pipelining (T14):
// each edge block = two 64-edge tiles; tile B's global gathers are issued
// right after tile A's X-ready barrier and stay in registers during A's MLP.
// LDS: X 64x192 bf16 swizzled (chunk c at c^(row&7)); H/H' 64x128 overlay.
// __launch_bounds__(256,5): reg cap 102 to hold the prefetch, no spill.
// ---------------------------------------------------------------------------
__global__ __launch_bounds__(256, 5)
void fused_k(const u16t* __restrict__ nfb, const u16t* __restrict__ stb,
             const float* __restrict__ nf, const float* __restrict__ ef,
             const float* __restrict__ b1, const float* __restrict__ b2,
             const float* __restrict__ b3, const float* __restrict__ ub1,
             const float* __restrict__ ub2, const int* __restrict__ eidx,
             const u16t* __restrict__ wp,
             float* __restrict__ out0, float* __restrict__ out1) {
    __shared__ __align__(16) u16t R[64 * 192];   // 24576 B
    __shared__ int dstL[64];
    const int tid  = threadIdx.x;
    const int lane = tid & 63;
    const int wv   = tid >> 6;
    const int lr   = lane & 15;
    const int qd   = lane >> 4;
    const int sw   = lr & 7;

    if (blockIdx.x >= NB_EDGE) {
        // ---------------- node role (barrier-free, wave-private H rows) ----
        const int n0  = (blockIdx.x - NB_EDGE) * 64;
        const int m16 = wv * 16;
        int nd  = n0 + m16 + lr;
        int ncl = nd < NN ? nd : NN - 1;          // clamp for loads

        fragc acc[8];
        #pragma unroll
        for (int n = 0; n < 8; n++) acc[n] = (fragc){0.f, 0.f, 0.f, 0.f};
        {
            const frag8* w = (const frag8*)(wp + U1P);
            #pragma unroll
            for (int ks = 0; ks < 3; ks++) {
                frag8 bfr;   // X[node=m16+lr][k] — serves as B-frag (col=lr)
                if (ks < 2) bfr = *(const frag8*)(nfb + (size_t)ncl * 64 + ks * 32 + qd * 8);
                else        bfr = *(const frag8*)(stb + (size_t)ncl * 32 + qd * 8);
                #pragma unroll
                for (int n = 0; n < 8; n++)
                    acc[n] = __builtin_amdgcn_mfma_f32_16x16x32_bf16(
                        w[(n * 3 + ks) * 64 + lane], bfr, acc[n], 0, 0, 0);
            }
        }
        // packed H write: lane holds H[node=m16+lr][n*16+qd*4 .. +4]
        #pragma unroll
        for (int n = 0; n < 8; n++) {
            float4 bq = *(const float4*)(ub1 + n * 16 + qd * 4);
            int cc = n * 2 + (qd >> 1);
            float v0 = acc[n][0] + bq.x; v0 = v0 > 0.f ? v0 : 0.f;
            float v1 = acc[n][1] + bq.y; v1 = v1 > 0.f ? v1 : 0.f;
            float v2 = acc[n][2] + bq.z; v2 = v2 > 0.f ? v2 : 0.f;
            float v3 = acc[n][3] + bq.w; v3 = v3 > 0.f ? v3 : 0.f;
            uint2 hw; hw.x = pack_bf2(v0, v1); hw.y = pack_bf2(v2, v3);
            *(uint2*)(R + (m16 + lr) * 128 + ((cc ^ sw) << 3) + (qd & 1) * 4) = hw;
        }
        // same-wave RAW on LDS: compiler inserts lgkmcnt; no barrier needed
        fragc a2[4];
        #pragma unroll
        for (int n = 0; n < 4; n++) a2[n] = (fragc){0.f, 0.f, 0.f, 0.f};
        {
            const frag8* w = (const frag8*)(wp + U2P);
            #pragma unroll
            for (int ks = 0; ks < 4; ks++) {
                int c = ks * 4 + qd;
                frag8 a = *(const frag8*)(R + (m16 + lr) * 128 + ((c ^ sw) << 3));
                #pragma unroll
                for (int n = 0; n < 4; n++)
                    a2[n] = __builtin_amdgcn_mfma_f32_16x16x32_bf16(
                        a, w[(n * 4 + ks) * 64 + lane], a2[n], 0, 0, 0);
            }
        }
        #pragma unroll
        for (int n = 0; n < 4; n++) {
            float bs = ub2[n * 16 + lr];
            #pragma unroll
            for (int r = 0; r < 4; r++) {
                int nd2 = n0 + m16 + qd * 4 + r;
                if (nd2 < NN) {
                    int col = n * 16 + lr;
                    out0[(size_t)nd2 * 64 + col] = nf[(size_t)nd2 * 64 + col] + a2[n][r] + bs;
                }
            }
        }
        return;
    }

    // ---------------- edge role: two 64-edge tiles, pipelined ----------------
    const int e0  = blockIdx.x * 128;
    const int el  = tid >> 2, p = tid & 3;     // 4 threads per edge row
    const int nb0 = 2 * wv, nb1 = 2 * wv + 1;

    uint4  gv[5];        // staged nfb[s]|nfb[d]|stb[s] chunks (per thread)
    float4 gf[2];        // staged ef
    int    gdst;

    // gather loads for edge (e) into registers (issue only; no LDS)
    auto LOADG = [&](int e) {
        int2 sd = *(const int2*)(eidx + 2 * e);
        int s = sd.x, d = sd.y;
        gdst = d;
        const uint4* nsb = (const uint4*)(nfb + (size_t)s * 64);
        const uint4* ndb = (const uint4*)(nfb + (size_t)d * 64);
        const uint4* spb = (const uint4*)(stb + (size_t)s * 32);
        #pragma unroll
        for (int j = 0; j < 5; j++) {
            int g = p + 4 * j;
            gv[j] = (g < 8) ? nsb[g] : (g < 16 ? ndb[g - 8] : spb[g - 16]);
        }
        const float4* epf = (const float4*)(ef + (size_t)e * 32);
        gf[0] = epf[p];
        gf[1] = epf[p + 4];
    };
    // write staged registers into swizzled X tile
    auto WRITEG = [&]() {
        u16t* xr = R + el * 192;
        const int k = el & 7;
        #pragma unroll
        for (int j = 0; j < 5; j++) {
            int g = p + 4 * j;
            int c = (g < 16) ? g : g + 4;       // stb chunks land at cols 160..191
            *(uint4*)(xr + ((c ^ k) << 3)) = gv[j];
        }
        #pragma unroll
        for (int q = 0; q < 2; q++) {
            int h = p + 4 * q;
            uint2 pk;
            pk.x = pack_bf2(gf[q].x, gf[q].y);
            pk.y = pack_bf2(gf[q].z, gf[q].w);
            int c = 16 + (h >> 1);              // ef at cols 128..159
            *(uint2*)(xr + ((c ^ k) << 3) + (h & 1) * 4) = pk;
        }
        if (p == 0) dstL[el] = gdst;
    };

    LOADG(e0 + el);                              // tile A gathers

    #pragma unroll
    for (int t = 0; t < 2; ++t) {
        WRITEG();
        __syncthreads();                         // B1: X_t + dstL visible
        if (t == 0) LOADG(e0 + 64 + el);         // issue tile B gathers NOW;
                                                 // they ride out A's whole MLP

        // ---- layer 1: H^T = W1^T . X^T ; wave owns n-blocks nb0,nb1
        fragc acc[2][4];
        #pragma unroll
        for (int i = 0; i < 2; i++)
            #pragma unroll
            for (int m = 0; m < 4; m++) acc[i][m] = (fragc){0.f, 0.f, 0.f, 0.f};
        {
            const frag8* w = (const frag8*)(wp + W1P);
            #pragma unroll
            for (int ks = 0; ks < 6; ks++) {
                frag8 w0 = w[(nb0 * 6 + ks) * 64 + lane];
                frag8 w1 = w[(nb1 * 6 + ks) * 64 + lane];
                int c = ks * 4 + qd;
                #pragma unroll
                for (int m = 0; m < 4; m++) {
                    frag8 x = *(const frag8*)(R + (m * 16 + lr) * 192 + ((c ^ sw) << 3));
                    acc[0][m] = __builtin_amdgcn_mfma_f32_16x16x32_bf16(w0, x, acc[0][m], 0, 0, 0);
                    acc[1][m] = __builtin_amdgcn_mfma_f32_16x16x32_bf16(w1, x, acc[1][m], 0, 0, 0);
                }
            }
        }
        __syncthreads();             // B2: all X reads done, R reusable as H
        #pragma unroll
        for (int i = 0; i < 2; i++) {
            int nb = nb0 + i;
            float4 bq = *(const float4*)(b1 + nb * 16 + qd * 4);
            int cc = nb * 2 + (qd >> 1);
            #pragma unroll
            for (int m = 0; m < 4; m++) {
                float v0 = acc[i][m][0] + bq.x; v0 = v0 > 0.f ? v0 : 0.f;
                float v1 = acc[i][m][1] + bq.y; v1 = v1 > 0.f ? v1 : 0.f;
                float v2 = acc[i][m][2] + bq.z; v2 = v2 > 0.f ? v2 : 0.f;
                float v3 = acc[i][m][3] + bq.w; v3 = v3 > 0.f ? v3 : 0.f;
                uint2 hw; hw.x = pack_bf2(v0, v1); hw.y = pack_bf2(v2, v3);
                *(uint2*)(R + (m * 16 + lr) * 128 + ((cc ^ sw) << 3) + (qd & 1) * 4) = hw;
            }
        }
        __syncthreads();             // B3: H complete

        // ---- layer 2: H' = W2^T . H^T
        #pragma unroll
        for (int i = 0; i < 2; i++)
            #pragma unroll
            for (int m = 0; m < 4; m++) acc[i][m] = (fragc){0.f, 0.f, 0.f, 0.f};
        {
            const frag8* w = (const frag8*)(wp + W2P);
            #pragma unroll
            for (int ks = 0; ks < 4; ks++) {
                frag8 w0 = w[(nb0 * 4 + ks) * 64 + lane];
                frag8 w1 = w[(nb1 * 4 + ks) * 64 + lane];
                int c = ks * 4 + qd;
                #pragma unroll
                for (int m = 0; m < 4; m++) {
                    frag8 x = *(const frag8*)(R + (m * 16 + lr) * 128 + ((c ^ sw) << 3));
                    acc[0][m] = __builtin_amdgcn_mfma_f32_16x16x32_bf16(w0, x, acc[0][m], 0, 0, 0);
                    acc[1][m] = __builtin_amdgcn_mfma_f32_16x16x32_bf16(w1, x, acc[1][m], 0, 0, 0);
                }
            }
        }
        __syncthreads();             // B4: all H reads done
        #pragma unroll
        for (int i = 0; i < 2; i++) {
            int nb = nb0 + i;
            float4 bq = *(const float4*)(b2 + nb * 16 + qd * 4);
            int cc = nb * 2 + (qd >> 1);
            #pragma unroll
            for (int m = 0; m < 4; m++) {
                float v0 = acc[i][m][0] + bq.x; v0 = v0 > 0.f ? v0 : 0.f;
                float v1 = acc[i][m][1] + bq.y; v1 = v1 > 0.f ? v1 : 0.f;
                float v2 = acc[i][m][2] + bq.z; v2 = v2 > 0.f ? v2 : 0.f;
                float v3 = acc[i][m][3] + bq.w; v3 = v3 > 0.f ? v3 : 0.f;
                uint2 hw; hw.x = pack_bf2(v0, v1); hw.y = pack_bf2(v2, v3);
                *(uint2*)(R + (m * 16 + lr) * 128 + ((cc ^ sw) << 3) + (qd & 1) * 4) = hw;
            }
        }
        __syncthreads();             // B5: H' complete

        // ---- layer 3 (original order -> coalesced atomics): wave owns 16 cols
        fragc a3[4];
        #pragma unroll
        for (int m = 0; m < 4; m++) a3[m] = (fragc){0.f, 0.f, 0.f, 0.f};
        {
            const frag8* w = (const frag8*)(wp + W3P);
            #pragma unroll
            for (int ks = 0; ks < 4; ks++) {
                frag8 wf = w[(wv * 4 + ks) * 64 + lane];
                int c = ks * 4 + qd;
                #pragma unroll
                for (int m = 0; m < 4; m++) {
                    frag8 a = *(const frag8*)(R + (m * 16 + lr) * 128 + ((c ^ sw) << 3));
                    a3[m] = __builtin_amdgcn_mfma_f32_16x16x32_bf16(a, wf, a3[m], 0, 0, 0);
                }
            }
        }
        // ---- epilogue: scalar atomic scatter-add straight from registers
        {
            float bs = b3[wv * 16 + lr];
            #pragma unroll
            for (int m = 0; m < 4; m++)
                #pragma unroll
                for (int r = 0; r < 4; r++) {
                    int row = m * 16 + qd * 4 + r;
                    atomicAdd(out1 + (size_t)dstL[row] * 64 + wv * 16 + lr,
                              a3[m][r] + bs);
                }
        }
        if (t == 0) __syncthreads(); // B6: L3 reads + dstL reads done; R reusable
    }
}

extern "C" void kernel_launch(void* const* d_in, const int* in_sizes, int n_in,
                              void* d_out, int out_size, void* d_ws, size_t ws_size,
                              hipStream_t stream) {
    const float* nf  = (const float*)d_in[0];
    const float* ef  = (const float*)d_in[1];
    const float* st  = (const float*)d_in[2];
    const float* mW1 = (const float*)d_in[3];
    const float* mb1 = (const float*)d_in[4];
    const float* mW2 = (const float*)d_in[5];
    const float* mb2 = (const float*)d_in[6];
    const float* mW3 = (const float*)d_in[7];
    const float* mb3 = (const float*)d_in[8];
    const float* uW1 = (const float*)d_in[9];
    const float* ub1 = (const float*)d_in[10];
    const float* uW2 = (const float*)d_in[11];
    const float* ub2 = (const float*)d_in[12];
    const int*  eidx = (const int*)d_in[13];

    float* out0 = (float*)d_out;
    float* out1 = out0 + (size_t)NN * 64;
    char*  ws   = (char*)d_ws;
    u16t*  wp   = (u16t*)ws;
    u16t*  nfb  = (u16t*)(ws + NFB_OFF);
    u16t*  stb  = (u16t*)(ws + STB_OFF);

    prep_k<<<PB_PACK + PB_ZERO + PB_NF + PB_ST, 256, 0, stream>>>(
        mW1, mW2, mW3, uW1, uW2, wp, (float4*)out1, nf, nfb, st, stb);
    fused_k<<<NB_EDGE + NB_NODE, 256, 0, stream>>>(
        nfb, stb, nf, ef, mb1, mb2, mb3, ub1, ub2, eidx, wp, out0, out1);
}

// Round 6
// 437.575 us; speedup vs baseline: 1.0547x; 1.0547x over previous
//
#include <hip/hip_runtime.h>
#include <stdint.h>

typedef unsigned short u16t;
typedef unsigned int   u32t;
typedef __attribute__((ext_vector_type(8))) short frag8;   // 8 bf16 = 4 VGPRs
typedef __attribute__((ext_vector_type(4))) float fragc;   // 4 fp32 acc

#define NN 50000
#define NE 800000
#define NB_EDGE 25000          // edge blocks (32 edges each; NE = 32*25000)
#define NB_NODE 1563           // node blocks (32 nodes each)

// packed-weight offsets in u16 elements within d_ws (weights: 139264 B)
#define W1P 0
#define W2P 24576
#define W3P 40960
#define U1P 49152
#define U2P 61440
// bf16 mirrors of nf/st in d_ws (byte offsets; both 16B-aligned)
#define NFB_OFF 139264                     // u16 nfb[NN*64]  (6.4 MB)
#define STB_OFF (NFB_OFF + 6400000)        // u16 stb[NN*32]  (3.2 MB)

// prep grid partition
#define PB_PACK 34
#define PB_ZERO 3125           // zero out1: NN*16 float4
#define PB_NF   1563           // cvt nf: NN*64 = 3.2M elems, 2048/block
#define PB_ST   782            // cvt st: NN*32 = 1.6M elems

__device__ __forceinline__ u16t f2bf(float f) {
    u32t x = __builtin_bit_cast(u32t, f);
    x = x + 0x7FFFu + ((x >> 16) & 1u);   // RNE
    return (u16t)(x >> 16);
}

__device__ __forceinline__ u32t pack_bf2(float x, float y) {
#if __has_builtin(__builtin_amdgcn_cvt_pk_bf16_f32)
    typedef __attribute__((ext_vector_type(2))) __bf16 bfv2;
    bfv2 r = __builtin_amdgcn_cvt_pk_bf16_f32(x, y);
    return __builtin_bit_cast(u32t, r);
#else
    return (u32t)f2bf(x) | ((u32t)f2bf(y) << 16);
#endif
}

// ---------------------------------------------------------------------------
// Weight prepack core: W (K x N row-major fp32) -> bf16 frag order.
// Packed layout serves as both B-frag (col=lane&15) and A-frag (row=lane&15).
// ---------------------------------------------------------------------------
__device__ __forceinline__ void prepack_one(int t, const float* w1, const float* w2,
                                            const float* w3, const float* u1,
                                            const float* u2, u16t* out) {
    const float* src; u16t* dst; int id, K, N;
    if (t < 3072)      { id = t;        K = 192; N = 128; src = w1; dst = out + W1P; }
    else if (t < 5120) { id = t - 3072; K = 128; N = 128; src = w2; dst = out + W2P; }
    else if (t < 6144) { id = t - 5120; K = 128; N = 64;  src = w3; dst = out + W3P; }
    else if (t < 7680) { id = t - 6144; K = 96;  N = 128; src = u1; dst = out + U1P; }
    else if (t < 8704) { id = t - 7680; K = 128; N = 64;  src = u2; dst = out + U2P; }
    else return;
    int lane = id & 63;
    int fl   = id >> 6;
    int ksteps = K >> 5;
    int nb = fl / ksteps, ks = fl - nb * ksteps;
    int n  = nb * 16 + (lane & 15);
    int k0 = ks * 32 + (lane >> 4) * 8;
    const float* s = src + (size_t)k0 * N + n;
    uint4 v;
    v.x = pack_bf2(s[0],           s[(size_t)N]);
    v.y = pack_bf2(s[2*(size_t)N], s[3*(size_t)N]);
    v.z = pack_bf2(s[4*(size_t)N], s[5*(size_t)N]);
    v.w = pack_bf2(s[6*(size_t)N], s[7*(size_t)N]);
    *(uint4*)(dst + (size_t)id * 8) = v;
}

// fused prep: prepack weights | zero out1 | cvt nf->bf16 | cvt st->bf16
__global__ void prep_k(const float* __restrict__ w1, const float* __restrict__ w2,
                       const float* __restrict__ w3, const float* __restrict__ u1,
                       const float* __restrict__ u2, u16t* __restrict__ wp,
                       float4* __restrict__ out1v,
                       const float* __restrict__ nf, u16t* __restrict__ nfb,
                       const float* __restrict__ st, u16t* __restrict__ stb) {
    int b = blockIdx.x;
    if (b < PB_PACK) {
        prepack_one(b * 256 + threadIdx.x, w1, w2, w3, u1, u2, wp);
    } else if (b < PB_PACK + PB_ZERO) {
        int i = (b - PB_PACK) * 256 + threadIdx.x;
        if (i < NN * 16) out1v[i] = make_float4(0.f, 0.f, 0.f, 0.f);
    } else if (b < PB_PACK + PB_ZERO + PB_NF) {
        int i = ((b - PB_PACK - PB_ZERO) * 256 + threadIdx.x) * 8;
        if (i < NN * 64) {
            float4 a = *(const float4*)(nf + i);
            float4 c = *(const float4*)(nf + i + 4);
            uint4 v;
            v.x = pack_bf2(a.x, a.y); v.y = pack_bf2(a.z, a.w);
            v.z = pack_bf2(c.x, c.y); v.w = pack_bf2(c.z, c.w);
            *(uint4*)(nfb + i) = v;
        }
    } else {
        int i = ((b - PB_PACK - PB_ZERO - PB_NF) * 256 + threadIdx.x) * 8;
        if (i < NN * 32) {
            float4 a = *(const float4*)(st + i);
            float4 c = *(const float4*)(st + i + 4);
            uint4 v;
            v.x = pack_bf2(a.x, a.y); v.y = pack_bf2(a.z, a.w);
            v.z = pack_bf2(c.x, c.y); v.w = pack_bf2(c.z, c.w);
            *(uint4*)(stb + i) = v;
        }
    }
}

// ---------------------------------------------------------------------------
// Fused main kernel — small-block edition for latency hiding:
// 32 edges (or 32 nodes) per 128-thread block, 2 waves, 12.4 KB LDS
// -> 12 independent blocks/CU (vs 6), 2-wave barriers, s_setprio on MFMA.
// LDS: X 32x192 bf16, chunk c of row stored at (c ^ (row&7)); H 32x128 overlay.
// L1/L2 use transposed mfma(W,X) -> packed conflict-free 8B H writes (R4-verified).
// ---------------------------------------------------------------------------
__global__ __launch_bounds__(128, 6)
void fused_k(const u16t* __restrict__ nfb, const u16t* __restrict__ stb,
             const float* __restrict__ nf, const float* __restrict__ ef,
             const float* __restrict__ b1, const float* __restrict__ b2,
             const float* __restrict__ b3, const float* __restrict__ ub1,
             const float* __restrict__ ub2, const int* __restrict__ eidx,
             const u16t* __restrict__ wp,
             float* __restrict__ out0, float* __restrict__ out1) {
    __shared__ __align__(16) u16t R[32 * 192];   // 12288 B
    __shared__ int dstL[32];
    const int tid  = threadIdx.x;
    const int lane = tid & 63;
    const int wv   = tid >> 6;                   // 0..1
    const int lr   = lane & 15;
    const int qd   = lane >> 4;
    const int sw   = lr & 7;

    if (blockIdx.x >= NB_EDGE) {
        // ---------------- node role (barrier-free, wave-private H rows) ----
        const int n0  = (blockIdx.x - NB_EDGE) * 32;
        const int m16 = wv * 16;
        int nd  = n0 + m16 + lr;
        int ncl = nd < NN ? nd : NN - 1;          // clamp for loads

        fragc acc[8];
        #pragma unroll
        for (int n = 0; n < 8; n++) acc[n] = (fragc){0.f, 0.f, 0.f, 0.f};
        {
            const frag8* w = (const frag8*)(wp + U1P);
            __builtin_amdgcn_s_setprio(1);
            #pragma unroll
            for (int ks = 0; ks < 3; ks++) {
                frag8 bfr;   // X[node=m16+lr][k] — B-frag (col=lr)
                if (ks < 2) bfr = *(const frag8*)(nfb + (size_t)ncl * 64 + ks * 32 + qd * 8);
                else        bfr = *(const frag8*)(stb + (size_t)ncl * 32 + qd * 8);
                #pragma unroll
                for (int n = 0; n < 8; n++)
                    acc[n] = __builtin_amdgcn_mfma_f32_16x16x32_bf16(
                        w[(n * 3 + ks) * 64 + lane], bfr, acc[n], 0, 0, 0);
            }
            __builtin_amdgcn_s_setprio(0);
        }
        // packed H write: lane holds H[node=m16+lr][n*16+qd*4 .. +4]
        #pragma unroll
        for (int n = 0; n < 8; n++) {
            float4 bq = *(const float4*)(ub1 + n * 16 + qd * 4);
            int cc = n * 2 + (qd >> 1);
            float v0 = acc[n][0] + bq.x; v0 = v0 > 0.f ? v0 : 0.f;
            float v1 = acc[n][1] + bq.y; v1 = v1 > 0.f ? v1 : 0.f;
            float v2 = acc[n][2] + bq.z; v2 = v2 > 0.f ? v2 : 0.f;
            float v3 = acc[n][3] + bq.w; v3 = v3 > 0.f ? v3 : 0.f;
            uint2 hw; hw.x = pack_bf2(v0, v1); hw.y = pack_bf2(v2, v3);
            *(uint2*)(R + (m16 + lr) * 128 + ((cc ^ sw) << 3) + (qd & 1) * 4) = hw;
        }
        // same-wave RAW on LDS: compiler inserts lgkmcnt; no barrier needed
        fragc a2[4];
        #pragma unroll
        for (int n = 0; n < 4; n++) a2[n] = (fragc){0.f, 0.f, 0.f, 0.f};
        {
            const frag8* w = (const frag8*)(wp + U2P);
            __builtin_amdgcn_s_setprio(1);
            #pragma unroll
            for (int ks = 0; ks < 4; ks++) {
                int c = ks * 4 + qd;
                frag8 a = *(const frag8*)(R + (m16 + lr) * 128 + ((c ^ sw) << 3));
                #pragma unroll
                for (int n = 0; n < 4; n++)
                    a2[n] = __builtin_amdgcn_mfma_f32_16x16x32_bf16(
                        a, w[(n * 4 + ks) * 64 + lane], a2[n], 0, 0, 0);
            }
            __builtin_amdgcn_s_setprio(0);
        }
        #pragma unroll
        for (int n = 0; n < 4; n++) {
            float bs = ub2[n * 16 + lr];
            #pragma unroll
            for (int r = 0; r < 4; r++) {
                int nd2 = n0 + m16 + qd * 4 + r;
                if (nd2 < NN) {
                    int col = n * 16 + lr;
                    out0[(size_t)nd2 * 64 + col] = nf[(size_t)nd2 * 64 + col] + a2[n][r] + bs;
                }
            }
        }
        return;
    }

    // ---------------- edge role: 32 edges, 2 waves ----------------
    const int e0 = blockIdx.x * 32;

    { // stage X (swizzled): chunks 0..15 = nfb[s]|nfb[d], 16..19 = ef, 20..23 = stb[s]
        int el = tid >> 2, p = tid & 3;          // 4 threads per edge row, el 0..31
        int e = e0 + el;
        int s = eidx[2 * e], d = eidx[2 * e + 1];
        const uint4* nsb = (const uint4*)(nfb + (size_t)s * 64);
        const uint4* ndb = (const uint4*)(nfb + (size_t)d * 64);
        const uint4* spb = (const uint4*)(stb + (size_t)s * 32);
        u16t* xr = R + el * 192;
        const int k = el & 7;
        #pragma unroll
        for (int g = p; g < 20; g += 4) {
            uint4 v; int c;
            if (g < 8)       { v = nsb[g];      c = g; }
            else if (g < 16) { v = ndb[g - 8];  c = g; }
            else             { v = spb[g - 16]; c = g + 4; }
            *(uint4*)(xr + ((c ^ k) << 3)) = v;
        }
        const float4* epf = (const float4*)(ef + (size_t)e * 32);
        #pragma unroll
        for (int h = p; h < 8; h += 4) {
            float4 v = epf[h];
            uint2 pk;
            pk.x = pack_bf2(v.x, v.y);
            pk.y = pack_bf2(v.z, v.w);
            int c = 16 + (h >> 1);
            *(uint2*)(xr + ((c ^ k) << 3) + (h & 1) * 4) = pk;
        }
        if (p == 0) dstL[el] = d;
    }
    __syncthreads();             // B1: X + dstL visible

    // ---- layer 1: H^T = W1^T . X^T ; wave owns n-blocks 4wv..4wv+3
    fragc acc[4][2];
    #pragma unroll
    for (int i = 0; i < 4; i++)
        #pragma unroll
        for (int m = 0; m < 2; m++) acc[i][m] = (fragc){0.f, 0.f, 0.f, 0.f};
    {
        const frag8* w = (const frag8*)(wp + W1P);
        __builtin_amdgcn_s_setprio(1);
        #pragma unroll
        for (int ks = 0; ks < 6; ks++) {
            frag8 wf[4];
            #pragma unroll
            for (int i = 0; i < 4; i++)
                wf[i] = w[((4 * wv + i) * 6 + ks) * 64 + lane];
            int c = ks * 4 + qd;
            #pragma unroll
            for (int m = 0; m < 2; m++) {
                frag8 x = *(const frag8*)(R + (m * 16 + lr) * 192 + ((c ^ sw) << 3));
                #pragma unroll
                for (int i = 0; i < 4; i++)
                    acc[i][m] = __builtin_amdgcn_mfma_f32_16x16x32_bf16(wf[i], x, acc[i][m], 0, 0, 0);
            }
        }
        __builtin_amdgcn_s_setprio(0);
    }
    __syncthreads();             // B2: all X reads done, R reusable as H
    // packed H write: lane holds H[edge=m*16+lr][nb*16+qd*4 .. +4]
    #pragma unroll
    for (int i = 0; i < 4; i++) {
        int nb = 4 * wv + i;
        float4 bq = *(const float4*)(b1 + nb * 16 + qd * 4);
        int cc = nb * 2 + (qd >> 1);
        #pragma unroll
        for (int m = 0; m < 2; m++) {
            float v0 = acc[i][m][0] + bq.x; v0 = v0 > 0.f ? v0 : 0.f;
            float v1 = acc[i][m][1] + bq.y; v1 = v1 > 0.f ? v1 : 0.f;
            float v2 = acc[i][m][2] + bq.z; v2 = v2 > 0.f ? v2 : 0.f;
            float v3 = acc[i][m][3] + bq.w; v3 = v3 > 0.f ? v3 : 0.f;
            uint2 hw; hw.x = pack_bf2(v0, v1); hw.y = pack_bf2(v2, v3);
            *(uint2*)(R + (m * 16 + lr) * 128 + ((cc ^ sw) << 3) + (qd & 1) * 4) = hw;
        }
    }
    __syncthreads();             // B3: H complete

    // ---- layer 2: H' = W2^T . H^T
    #pragma unroll
    for (int i = 0; i < 4; i++)
        #pragma unroll
        for (int m = 0; m < 2; m++) acc[i][m] = (fragc){0.f, 0.f, 0.f, 0.f};
    {
        const frag8* w = (const frag8*)(wp + W2P);
        __builtin_amdgcn_s_setprio(1);
        #pragma unroll
        for (int ks = 0; ks < 4; ks++) {
            frag8 wf[4];
            #pragma unroll
            for (int i = 0; i < 4; i++)
                wf[i] = w[((4 * wv + i) * 4 + ks) * 64 + lane];
            int c = ks * 4 + qd;
            #pragma unroll
            for (int m = 0; m < 2; m++) {
                frag8 x = *(const frag8*)(R + (m * 16 + lr) * 128 + ((c ^ sw) << 3));
                #pragma unroll
                for (int i = 0; i < 4; i++)
                    acc[i][m] = __builtin_amdgcn_mfma_f32_16x16x32_bf16(wf[i], x, acc[i][m], 0, 0, 0);
            }
        }
        __builtin_amdgcn_s_setprio(0);
    }
    __syncthreads();             // B4: all H reads done
    #pragma unroll
    for (int i = 0; i < 4; i++) {
        int nb = 4 * wv + i;
        float4 bq = *(const float4*)(b2 + nb * 16 + qd * 4);
        int cc = nb * 2 + (qd >> 1);
        #pragma unroll
        for (int m = 0; m < 2; m++) {
            float v0 = acc[i][m][0] + bq.x; v0 = v0 > 0.f ? v0 : 0.f;
            float v1 = acc[i][m][1] + bq.y; v1 = v1 > 0.f ? v1 : 0.f;
            float v2 = acc[i][m][2] + bq.z; v2 = v2 > 0.f ? v2 : 0.f;
            float v3 = acc[i][m][3] + bq.w; v3 = v3 > 0.f ? v3 : 0.f;
            uint2 hw; hw.x = pack_bf2(v0, v1); hw.y = pack_bf2(v2, v3);
            *(uint2*)(R + (m * 16 + lr) * 128 + ((cc ^ sw) << 3) + (qd & 1) * 4) = hw;
        }
    }
    __syncthreads();             // B5: H' complete

    // ---- layer 3 (standard order -> coalesced atomics): wave owns nb 2wv,2wv+1
    fragc a3[2][2];
    #pragma unroll
    for (int i = 0; i < 2; i++)
        #pragma unroll
        for (int m = 0; m < 2; m++) a3[i][m] = (fragc){0.f, 0.f, 0.f, 0.f};
    {
        const frag8* w = (const frag8*)(wp + W3P);
        __builtin_amdgcn_s_setprio(1);
        #pragma unroll
        for (int ks = 0; ks < 4; ks++) {
            frag8 wf[2];
            #pragma unroll
            for (int i = 0; i < 2; i++)
                wf[i] = w[((2 * wv + i) * 4 + ks) * 64 + lane];
            int c = ks * 4 + qd;
            #pragma unroll
            for (int m = 0; m < 2; m++) {
                frag8 a = *(const frag8*)(R + (m * 16 + lr) * 128 + ((c ^ sw) << 3));
                #pragma unroll
                for (int i = 0; i < 2; i++)
                    a3[i][m] = __builtin_amdgcn_mfma_f32_16x16x32_bf16(a, wf[i], a3[i][m], 0, 0, 0);
            }
        }
        __builtin_amdgcn_s_setprio(0);
    }
    // ---- epilogue: scalar atomic scatter-add straight from registers
    #pragma unroll
    for (int i = 0; i < 2; i++) {
        int nb = 2 * wv + i;
        float bs = b3[nb * 16 + lr];
        #pragma unroll
        for (int m = 0; m < 2; m++)
            #pragma unroll
            for (int r = 0; r < 4; r++) {
                int row = m * 16 + qd * 4 + r;
                atomicAdd(out1 + (size_t)dstL[row] * 64 + nb * 16 + lr,
                          a3[i][m][r] + bs);
            }
    }
}

extern "C" void kernel_launch(void* const* d_in, const int* in_sizes, int n_in,
                              void* d_out, int out_size, void* d_ws, size_t ws_size,
                              hipStream_t stream) {
    const float* nf  = (const float*)d_in[0];
    const float* ef  = (const float*)d_in[1];
    const float* st  = (const float*)d_in[2];
    const float* mW1 = (const float*)d_in[3];
    const float* mb1 = (const float*)d_in[4];
    const float* mW2 = (const float*)d_in[5];
    const float* mb2 = (const float*)d_in[6];
    const float* mW3 = (const float*)d_in[7];
    const float* mb3 = (const float*)d_in[8];
    const float* uW1 = (const float*)d_in[9];
    const float* ub1 = (const float*)d_in[10];
    const float* uW2 = (const float*)d_in[11];
    const float* ub2 = (const float*)d_in[12];
    const int*  eidx = (const int*)d_in[13];

    float* out0 = (float*)d_out;
    float* out1 = out0 + (size_t)NN * 64;
    char*  ws   = (char*)d_ws;
    u16t*  wp   = (u16t*)ws;
    u16t*  nfb  = (u16t*)(ws + NFB_OFF);
    u16t*  stb  = (u16t*)(ws + STB_OFF);

    prep_k<<<PB_PACK + PB_ZERO + PB_NF + PB_ST, 256, 0, stream>>>(
        mW1, mW2, mW3, uW1, uW2, wp, (float4*)out1, nf, nfb, st, stb);
    fused_k<<<NB_EDGE + NB_NODE, 128, 0, stream>>>(
        nfb, stb, nf, ef, mb1, mb2, mb3, ub1, ub2, eidx, wp, out0, out1);
}

// Round 7
// 367.614 us; speedup vs baseline: 1.2554x; 1.1903x over previous
//
#include <hip/hip_runtime.h>
#include <stdint.h>

typedef unsigned short u16t;
typedef unsigned int   u32t;
typedef __attribute__((ext_vector_type(8))) short frag8;   // 8 bf16 = 4 VGPRs
typedef __attribute__((ext_vector_type(4))) float fragc;   // 4 fp32 acc

#define NN 50000
#define NE 800000
#define NB_EDGE 12500          // edge blocks (64 edges each; NE = 64*12500 exactly)
#define NB_NODE 782            // node-MLP blocks (64 nodes each)

// packed-weight offsets in u16 elements within d_ws (weights: 139264 B)
#define W1P 0
#define W2P 24576
#define W3P 40960
#define U1P 49152
#define U2P 61440

// prep grid partition (prep is now tiny: weight pack + out1 zero only)
#define PB_PACK 34
#define PB_ZERO 782            // zero out1: NN*16 float4, 4 per thread

__device__ __forceinline__ u16t f2bf(float f) {
    u32t x = __builtin_bit_cast(u32t, f);
    x = x + 0x7FFFu + ((x >> 16) & 1u);   // RNE
    return (u16t)(x >> 16);
}

__device__ __forceinline__ u32t pack_bf2(float x, float y) {
#if __has_builtin(__builtin_amdgcn_cvt_pk_bf16_f32)
    typedef __attribute__((ext_vector_type(2))) __bf16 bfv2;
    bfv2 r = __builtin_amdgcn_cvt_pk_bf16_f32(x, y);
    return __builtin_bit_cast(u32t, r);
#else
    return (u32t)f2bf(x) | ((u32t)f2bf(y) << 16);
#endif
}

// pack 8 consecutive fp32 (two float4) -> one 16B bf16 chunk
__device__ __forceinline__ uint4 pack_chunk(float4 a, float4 b) {
    uint4 v;
    v.x = pack_bf2(a.x, a.y); v.y = pack_bf2(a.z, a.w);
    v.z = pack_bf2(b.x, b.y); v.w = pack_bf2(b.z, b.w);
    return v;
}

// ---------------------------------------------------------------------------
// Weight prepack core: W (K x N row-major fp32) -> bf16 frag order.
// Packed layout serves as both B-frag (col=lane&15) and A-frag (row=lane&15).
// ---------------------------------------------------------------------------
__device__ __forceinline__ void prepack_one(int t, const float* w1, const float* w2,
                                            const float* w3, const float* u1,
                                            const float* u2, u16t* out) {
    const float* src; u16t* dst; int id, K, N;
    if (t < 3072)      { id = t;        K = 192; N = 128; src = w1; dst = out + W1P; }
    else if (t < 5120) { id = t - 3072; K = 128; N = 128; src = w2; dst = out + W2P; }
    else if (t < 6144) { id = t - 5120; K = 128; N = 64;  src = w3; dst = out + W3P; }
    else if (t < 7680) { id = t - 6144; K = 96;  N = 128; src = u1; dst = out + U1P; }
    else if (t < 8704) { id = t - 7680; K = 128; N = 64;  src = u2; dst = out + U2P; }
    else return;
    int lane = id & 63;
    int fl   = id >> 6;
    int ksteps = K >> 5;
    int nb = fl / ksteps, ks = fl - nb * ksteps;
    int n  = nb * 16 + (lane & 15);
    int k0 = ks * 32 + (lane >> 4) * 8;
    const float* s = src + (size_t)k0 * N + n;
    uint4 v;
    v.x = pack_bf2(s[0],           s[(size_t)N]);
    v.y = pack_bf2(s[2*(size_t)N], s[3*(size_t)N]);
    v.z = pack_bf2(s[4*(size_t)N], s[5*(size_t)N]);
    v.w = pack_bf2(s[6*(size_t)N], s[7*(size_t)N]);
    *(uint4*)(dst + (size_t)id * 8) = v;
}

// tiny prep: prepack weights | zero out1
__global__ void prep_k(const float* __restrict__ w1, const float* __restrict__ w2,
                       const float* __restrict__ w3, const float* __restrict__ u1,
                       const float* __restrict__ u2, u16t* __restrict__ wp,
                       float4* __restrict__ out1v) {
    int b = blockIdx.x;
    if (b < PB_PACK) {
        prepack_one(b * 256 + threadIdx.x, w1, w2, w3, u1, u2, wp);
    } else {
        int i0 = (b - PB_PACK) * 1024 + threadIdx.x;
        float4 z = make_float4(0.f, 0.f, 0.f, 0.f);
        #pragma unroll
        for (int j = 0; j < 4; j++) {
            int i = i0 + j * 256;
            if (i < NN * 16) out1v[i] = z;
        }
    }
}

// ---------------------------------------------------------------------------
// Fused main kernel — R4 body (proven ≈ R0), but staging reads fp32 nf/st
// directly (cvt_pk in staging); no bf16 mirrors, no mirror prep passes.
// LDS: X 64x192 bf16, chunk c of row stored at (c ^ (row&7)); H 64x128 overlay.
// L1/L2 use transposed mfma(W,X) -> packed conflict-free 8B H writes.
// ---------------------------------------------------------------------------
__global__ __launch_bounds__(256, 6)
void fused_k(const float* __restrict__ nf, const float* __restrict__ st,
             const float* __restrict__ ef,
             const float* __restrict__ b1, const float* __restrict__ b2,
             const float* __restrict__ b3, const float* __restrict__ ub1,
             const float* __restrict__ ub2, const int* __restrict__ eidx,
             const u16t* __restrict__ wp,
             float* __restrict__ out0, float* __restrict__ out1) {
    __shared__ __align__(16) u16t R[64 * 192];   // 24576 B
    __shared__ int dstL[64];
    const int tid  = threadIdx.x;
    const int lane = tid & 63;
    const int wv   = tid >> 6;
    const int lr   = lane & 15;
    const int qd   = lane >> 4;
    const int sw   = lr & 7;

    if (blockIdx.x >= NB_EDGE) {
        // ---------------- node role (barrier-free, wave-private H rows) ----
        const int n0  = (blockIdx.x - NB_EDGE) * 64;
        const int m16 = wv * 16;
        int nd  = n0 + m16 + lr;
        int ncl = nd < NN ? nd : NN - 1;          // clamp for loads
        const float4* nr = (const float4*)(nf + (size_t)ncl * 64);
        const float4* sr = (const float4*)(st + (size_t)ncl * 32);

        fragc acc[8];
        #pragma unroll
        for (int n = 0; n < 8; n++) acc[n] = (fragc){0.f, 0.f, 0.f, 0.f};
        {
            const frag8* w = (const frag8*)(wp + U1P);
            #pragma unroll
            for (int ks = 0; ks < 3; ks++) {
                float4 a, b;
                if (ks < 2) { a = nr[ks * 8 + qd * 2]; b = nr[ks * 8 + qd * 2 + 1]; }
                else        { a = sr[qd * 2];          b = sr[qd * 2 + 1]; }
                frag8 bfr = __builtin_bit_cast(frag8, pack_chunk(a, b));
                #pragma unroll
                for (int n = 0; n < 8; n++)
                    acc[n] = __builtin_amdgcn_mfma_f32_16x16x32_bf16(
                        w[(n * 3 + ks) * 64 + lane], bfr, acc[n], 0, 0, 0);
            }
        }
        // packed H write: lane holds H[node=m16+lr][n*16+qd*4 .. +4]
        #pragma unroll
        for (int n = 0; n < 8; n++) {
            float4 bq = *(const float4*)(ub1 + n * 16 + qd * 4);
            int cc = n * 2 + (qd >> 1);
            float v0 = acc[n][0] + bq.x; v0 = v0 > 0.f ? v0 : 0.f;
            float v1 = acc[n][1] + bq.y; v1 = v1 > 0.f ? v1 : 0.f;
            float v2 = acc[n][2] + bq.z; v2 = v2 > 0.f ? v2 : 0.f;
            float v3 = acc[n][3] + bq.w; v3 = v3 > 0.f ? v3 : 0.f;
            uint2 hw; hw.x = pack_bf2(v0, v1); hw.y = pack_bf2(v2, v3);
            *(uint2*)(R + (m16 + lr) * 128 + ((cc ^ sw) << 3) + (qd & 1) * 4) = hw;
        }
        // same-wave RAW on LDS: compiler inserts lgkmcnt; no barrier needed
        fragc a2[4];
        #pragma unroll
        for (int n = 0; n < 4; n++) a2[n] = (fragc){0.f, 0.f, 0.f, 0.f};
        {
            const frag8* w = (const frag8*)(wp + U2P);
            #pragma unroll
            for (int ks = 0; ks < 4; ks++) {
                int c = ks * 4 + qd;
                frag8 a = *(const frag8*)(R + (m16 + lr) * 128 + ((c ^ sw) << 3));
                #pragma unroll
                for (int n = 0; n < 4; n++)
                    a2[n] = __builtin_amdgcn_mfma_f32_16x16x32_bf16(
                        a, w[(n * 4 + ks) * 64 + lane], a2[n], 0, 0, 0);
            }
        }
        #pragma unroll
        for (int n = 0; n < 4; n++) {
            float bs = ub2[n * 16 + lr];
            #pragma unroll
            for (int r = 0; r < 4; r++) {
                int nd2 = n0 + m16 + qd * 4 + r;
                if (nd2 < NN) {
                    int col = n * 16 + lr;
                    out0[(size_t)nd2 * 64 + col] = nf[(size_t)nd2 * 64 + col] + a2[n][r] + bs;
                }
            }
        }
        return;
    }

    // ---------------- edge role ----------------
    const int e0  = blockIdx.x * 64;
    const int nb0 = 2 * wv, nb1 = 2 * wv + 1;

    { // stage X (swizzled) from fp32 sources; cvt_pk inline.
      // chunks 0..7 = nf[s], 8..15 = nf[d], 16..19 = ef, 20..23 = st[s]
        int el = tid >> 2, p = tid & 3;
        int e = e0 + el;
        int s = eidx[2 * e], d = eidx[2 * e + 1];
        const float4* nsf = (const float4*)(nf + (size_t)s * 64);
        const float4* ndf = (const float4*)(nf + (size_t)d * 64);
        const float4* stf = (const float4*)(st + (size_t)s * 32);
        const float4* eff = (const float4*)(ef + (size_t)e * 32);
        u16t* xr = R + el * 192;
        const int k = el & 7;
        #pragma unroll
        for (int g = p; g < 8; g += 4) {
            uint4 v = pack_chunk(nsf[2 * g], nsf[2 * g + 1]);
            *(uint4*)(xr + ((g ^ k) << 3)) = v;
            uint4 u = pack_chunk(ndf[2 * g], ndf[2 * g + 1]);
            *(uint4*)(xr + (((g + 8) ^ k) << 3)) = u;
        }
        {
            uint4 v = pack_chunk(eff[2 * p], eff[2 * p + 1]);
            *(uint4*)(xr + (((16 + p) ^ k) << 3)) = v;
            uint4 u = pack_chunk(stf[2 * p], stf[2 * p + 1]);
            *(uint4*)(xr + (((20 + p) ^ k) << 3)) = u;
        }
        if (p == 0) dstL[el] = d;
    }
    __syncthreads();             // B1: X + dstL visible

    // ---- layer 1: H^T = W1^T . X^T ; wave owns n-blocks nb0,nb1
    fragc acc[2][4];
    #pragma unroll
    for (int i = 0; i < 2; i++)
        #pragma unroll
        for (int m = 0; m < 4; m++) acc[i][m] = (fragc){0.f, 0.f, 0.f, 0.f};
    {
        const frag8* w = (const frag8*)(wp + W1P);
        #pragma unroll
        for (int ks = 0; ks < 6; ks++) {
            frag8 w0 = w[(nb0 * 6 + ks) * 64 + lane];
            frag8 w1 = w[(nb1 * 6 + ks) * 64 + lane];
            int c = ks * 4 + qd;
            #pragma unroll
            for (int m = 0; m < 4; m++) {
                frag8 x = *(const frag8*)(R + (m * 16 + lr) * 192 + ((c ^ sw) << 3));
                acc[0][m] = __builtin_amdgcn_mfma_f32_16x16x32_bf16(w0, x, acc[0][m], 0, 0, 0);
                acc[1][m] = __builtin_amdgcn_mfma_f32_16x16x32_bf16(w1, x, acc[1][m], 0, 0, 0);
            }
        }
    }
    __syncthreads();             // B2: all X reads done, R reusable as H
    // packed H write: lane holds H[edge=m*16+lr][nb*16+qd*4 .. +4]
    #pragma unroll
    for (int i = 0; i < 2; i++) {
        int nb = nb0 + i;
        float4 bq = *(const float4*)(b1 + nb * 16 + qd * 4);
        int cc = nb * 2 + (qd >> 1);
        #pragma unroll
        for (int m = 0; m < 4; m++) {
            float v0 = acc[i][m][0] + bq.x; v0 = v0 > 0.f ? v0 : 0.f;
            float v1 = acc[i][m][1] + bq.y; v1 = v1 > 0.f ? v1 : 0.f;
            float v2 = acc[i][m][2] + bq.z; v2 = v2 > 0.f ? v2 : 0.f;
            float v3 = acc[i][m][3] + bq.w; v3 = v3 > 0.f ? v3 : 0.f;
            uint2 hw; hw.x = pack_bf2(v0, v1); hw.y = pack_bf2(v2, v3);
            *(uint2*)(R + (m * 16 + lr) * 128 + ((cc ^ sw) << 3) + (qd & 1) * 4) = hw;
        }
    }
    __syncthreads();             // B3: H complete

    // ---- layer 2: H' = W2^T . H^T
    #pragma unroll
    for (int i = 0; i < 2; i++)
        #pragma unroll
        for (int m = 0; m < 4; m++) acc[i][m] = (fragc){0.f, 0.f, 0.f, 0.f};
    {
        const frag8* w = (const frag8*)(wp + W2P);
        #pragma unroll
        for (int ks = 0; ks < 4; ks++) {
            frag8 w0 = w[(nb0 * 4 + ks) * 64 + lane];
            frag8 w1 = w[(nb1 * 4 + ks) * 64 + lane];
            int c = ks * 4 + qd;
            #pragma unroll
            for (int m = 0; m < 4; m++) {
                frag8 x = *(const frag8*)(R + (m * 16 + lr) * 128 + ((c ^ sw) << 3));
                acc[0][m] = __builtin_amdgcn_mfma_f32_16x16x32_bf16(w0, x, acc[0][m], 0, 0, 0);
                acc[1][m] = __builtin_amdgcn_mfma_f32_16x16x32_bf16(w1, x, acc[1][m], 0, 0, 0);
            }
        }
    }
    __syncthreads();             // B4: all H reads done
    #pragma unroll
    for (int i = 0; i < 2; i++) {
        int nb = nb0 + i;
        float4 bq = *(const float4*)(b2 + nb * 16 + qd * 4);
        int cc = nb * 2 + (qd >> 1);
        #pragma unroll
        for (int m = 0; m < 4; m++) {
            float v0 = acc[i][m][0] + bq.x; v0 = v0 > 0.f ? v0 : 0.f;
            float v1 = acc[i][m][1] + bq.y; v1 = v1 > 0.f ? v1 : 0.f;
            float v2 = acc[i][m][2] + bq.z; v2 = v2 > 0.f ? v2 : 0.f;
            float v3 = acc[i][m][3] + bq.w; v3 = v3 > 0.f ? v3 : 0.f;
            uint2 hw; hw.x = pack_bf2(v0, v1); hw.y = pack_bf2(v2, v3);
            *(uint2*)(R + (m * 16 + lr) * 128 + ((cc ^ sw) << 3) + (qd & 1) * 4) = hw;
        }
    }
    __syncthreads();             // B5: H' complete

    // ---- layer 3 (standard order -> coalesced atomics): wave owns 16 cols
    fragc a3[4];
    #pragma unroll
    for (int m = 0; m < 4; m++) a3[m] = (fragc){0.f, 0.f, 0.f, 0.f};
    {
        const frag8* w = (const frag8*)(wp + W3P);
        #pragma unroll
        for (int ks = 0; ks < 4; ks++) {
            frag8 wf = w[(wv * 4 + ks) * 64 + lane];
            int c = ks * 4 + qd;
            #pragma unroll
            for (int m = 0; m < 4; m++) {
                frag8 a = *(const frag8*)(R + (m * 16 + lr) * 128 + ((c ^ sw) << 3));
                a3[m] = __builtin_amdgcn_mfma_f32_16x16x32_bf16(a, wf, a3[m], 0, 0, 0);
            }
        }
    }
    // ---- epilogue: scalar atomic scatter-add straight from registers
    {
        float bs = b3[wv * 16 + lr];
        #pragma unroll
        for (int m = 0; m < 4; m++)
            #pragma unroll
            for (int r = 0; r < 4; r++) {
                int row = m * 16 + qd * 4 + r;
                atomicAdd(out1 + (size_t)dstL[row] * 64 + wv * 16 + lr,
                          a3[m][r] + bs);
            }
    }
}

extern "C" void kernel_launch(void* const* d_in, const int* in_sizes, int n_in,
                              void* d_out, int out_size, void* d_ws, size_t ws_size,
                              hipStream_t stream) {
    const float* nf  = (const float*)d_in[0];
    const float* ef  = (const float*)d_in[1];
    const float* st  = (const float*)d_in[2];
    const float* mW1 = (const float*)d_in[3];
    const float* mb1 = (const float*)d_in[4];
    const float* mW2 = (const float*)d_in[5];
    const float* mb2 = (const float*)d_in[6];
    const float* mW3 = (const float*)d_in[7];
    const float* mb3 = (const float*)d_in[8];
    const float* uW1 = (const float*)d_in[9];
    const float* ub1 = (const float*)d_in[10];
    const float* uW2 = (const float*)d_in[11];
    const float* ub2 = (const float*)d_in[12];
    const int*  eidx = (const int*)d_in[13];

    float* out0 = (float*)d_out;
    float* out1 = out0 + (size_t)NN * 64;
    u16t*  wp   = (u16t*)d_ws;

    prep_k<<<PB_PACK + PB_ZERO, 256, 0, stream>>>(
        mW1, mW2, mW3, uW1, uW2, wp, (float4*)out1);
    fused_k<<<NB_EDGE + NB_NODE, 256, 0, stream>>>(
        nf, st, ef, mb1, mb2, mb3, ub1, ub2, eidx, wp, out0, out1);
}